// Round 1
// baseline (75.124 us; speedup 1.0000x reference)
//
#include <hip/hip_runtime.h>

#define EPS 1e-8f
#define LAM 0.01f

constexpr int BS = 256;
constexpr int L  = 2048;
constexpr int N  = 128;
constexpr int CHUNK  = 128;          // rows per block
constexpr int NCHUNK = L / CHUNK;    // 16

// ws layout: [0..BS)   = S1 per batch (sum of Rp over masked rows)
//            [BS..2BS) = S2 per batch (sum of Rp^2 over masked rows)

__global__ void zero_ws_kernel(float* __restrict__ ws) {
    int i = blockIdx.x * blockDim.x + threadIdx.x;
    if (i < 2 * BS) ws[i] = 0.0f;
}

__global__ __launch_bounds__(256) void rp_kernel(
    const float* __restrict__ w,      // [BS][L][N]
    const float* __restrict__ price,  // [BS][L+1][N]
    const int*  __restrict__ pred_sz, // [BS]
    float* __restrict__ ws)
{
    const int b     = blockIdx.x / NCHUNK;
    const int chunk = blockIdx.x % NCHUNK;
    const int n     = pred_sz[b];

    const int start = chunk * CHUNK;
    if (start >= n) return;                       // fully-masked chunk: skip all loads
    const int end = min(start + CHUNK, n);

    const int tid  = threadIdx.x;
    const int grp  = tid >> 5;    // 32-lane group id within block: 0..7
    const int lane = tid & 31;

    float s1 = 0.0f, s2 = 0.0f;

    // Each 32-lane group processes one row (128 floats) per iteration:
    // 32 lanes x float4 = 128 elements.
    for (int l = start + grp; l < end; l += 8) {
        const size_t wbase = ((size_t)b * L + l) * N;
        const size_t pbase = ((size_t)b * (L + 1) + l) * N;

        const float4 wv = *reinterpret_cast<const float4*>(w     + wbase + lane * 4);
        const float4 pi = *reinterpret_cast<const float4*>(price + pbase + lane * 4);
        const float4 pj = *reinterpret_cast<const float4*>(price + pbase + N + lane * 4);

        float r0 = (pj.x - pi.x) / pi.x;  r0 = (r0 <= 2.0f) ? r0 : 0.0f;
        float r1 = (pj.y - pi.y) / pi.y;  r1 = (r1 <= 2.0f) ? r1 : 0.0f;
        float r2 = (pj.z - pi.z) / pi.z;  r2 = (r2 <= 2.0f) ? r2 : 0.0f;
        float r3 = (pj.w - pi.w) / pi.w;  r3 = (r3 <= 2.0f) ? r3 : 0.0f;

        float acc = wv.x * r0 + wv.y * r1 + wv.z * r2 + wv.w * r3;

        // reduce across the 32-lane group (xor masks < 32 stay in-group)
        #pragma unroll
        for (int m = 1; m < 32; m <<= 1)
            acc += __shfl_xor(acc, m);

        if (lane == 0) {              // acc == Rp[b][l]
            s1 += acc;
            s2 += acc * acc;
        }
    }

    __shared__ float ls1[8], ls2[8];
    if (lane == 0) { ls1[grp] = s1; ls2[grp] = s2; }
    __syncthreads();
    if (tid == 0) {
        float t1 = 0.0f, t2 = 0.0f;
        #pragma unroll
        for (int i = 0; i < 8; ++i) { t1 += ls1[i]; t2 += ls2[i]; }
        atomicAdd(&ws[b],      t1);
        atomicAdd(&ws[BS + b], t2);
    }
}

__global__ __launch_bounds__(256) void final_kernel(
    const float* __restrict__ ws,
    const int*  __restrict__ pred_sz,
    float* __restrict__ out)
{
    const int b = threadIdx.x;   // 256 threads, one per batch
    const float n  = (float)pred_sz[b];
    const float s1 = ws[b];
    const float s2 = ws[BS + b];

    const float E     = s1 / n;
    const float var   = (s2 - n * E * E) / (n - 1.0f);
    const float denom = sqrtf(var + EPS);
    const float sharpe      = E / denom;
    const float sharpe_list = E - LAM / denom;

    __shared__ float red[4][BS];
    red[0][b] = sharpe_list;
    red[1][b] = sharpe;
    red[2][b] = E;
    red[3][b] = var;
    __syncthreads();

    #pragma unroll
    for (int s = BS / 2; s > 0; s >>= 1) {
        if (b < s) {
            red[0][b] += red[0][b + s];
            red[1][b] += red[1][b + s];
            red[2][b] += red[2][b + s];
            red[3][b] += red[3][b + s];
        }
        __syncthreads();
    }

    if (b == 0) {
        out[0] = -red[0][0] / (float)BS;
        out[1] = -red[1][0] / (float)BS;
        out[2] =  red[2][0] / (float)BS;
        out[3] =  red[3][0] / (float)BS;
    }
}

extern "C" void kernel_launch(void* const* d_in, const int* in_sizes, int n_in,
                              void* d_out, int out_size, void* d_ws, size_t ws_size,
                              hipStream_t stream) {
    const float* w     = (const float*)d_in[0];  // pred_weights [256][2048][128]
    const float* price = (const float*)d_in[1];  // price_list   [256][2049][128]
    const int*   psz   = (const int*)d_in[2];    // pred_sz      [256]
    float* out = (float*)d_out;
    float* ws  = (float*)d_ws;

    zero_ws_kernel<<<2, 256, 0, stream>>>(ws);
    rp_kernel<<<BS * NCHUNK, 256, 0, stream>>>(w, price, psz, ws);
    final_kernel<<<1, BS, 0, stream>>>(ws, psz, out);
}

// Round 2
// 67.629 us; speedup vs baseline: 1.1108x; 1.1108x over previous
//
#include <hip/hip_runtime.h>

#define EPS 1e-8f
#define LAM 0.01f

constexpr int BS = 256;
constexpr int L  = 2048;
constexpr int N  = 128;
constexpr int CHUNK  = 128;          // rows per block
constexpr int NCHUNK = L / CHUNK;    // 16

// ws layout (floats):
//   [0              .. BS*NCHUNK)   = S1 partial per (batch, chunk)
//   [BS*NCHUNK      .. 2*BS*NCHUNK) = S2 partial per (batch, chunk)
// Blocks write only live chunks; finalize reads only live chunks, so no
// pre-zeroing is needed and every replay rewrites the same slots.

__global__ __launch_bounds__(256) void rp_kernel(
    const float* __restrict__ w,      // [BS][L][N]
    const float* __restrict__ price,  // [BS][L+1][N]
    const int*  __restrict__ pred_sz, // [BS]
    float* __restrict__ ws)
{
    const int b     = blockIdx.x / NCHUNK;
    const int chunk = blockIdx.x % NCHUNK;
    const int n     = pred_sz[b];

    const int start = chunk * CHUNK;
    if (start >= n) return;                       // fully-masked chunk: no loads, no writes
    const int end = min(start + CHUNK, n);

    const int tid  = threadIdx.x;
    const int grp  = tid >> 5;    // 32-lane group id within block: 0..7
    const int lane = tid & 31;

    float s1 = 0.0f, s2 = 0.0f;

    // Each 32-lane group processes one row (128 floats) per iteration.
    const int l0 = start + grp;
    const float* wp = w     + ((size_t)b * L       + l0) * N + lane * 4;
    const float* pp = price + ((size_t)b * (L + 1) + l0) * N + lane * 4;

    #pragma unroll 4
    for (int l = l0; l < end; l += 8, wp += 8 * N, pp += 8 * N) {
        const float4 wv = *reinterpret_cast<const float4*>(wp);
        const float4 pi = *reinterpret_cast<const float4*>(pp);
        const float4 pj = *reinterpret_cast<const float4*>(pp + N);

        float r0 = (pj.x - pi.x) * __builtin_amdgcn_rcpf(pi.x);
        float r1 = (pj.y - pi.y) * __builtin_amdgcn_rcpf(pi.y);
        float r2 = (pj.z - pi.z) * __builtin_amdgcn_rcpf(pi.z);
        float r3 = (pj.w - pi.w) * __builtin_amdgcn_rcpf(pi.w);
        r0 = (r0 <= 2.0f) ? r0 : 0.0f;
        r1 = (r1 <= 2.0f) ? r1 : 0.0f;
        r2 = (r2 <= 2.0f) ? r2 : 0.0f;
        r3 = (r3 <= 2.0f) ? r3 : 0.0f;

        float acc = wv.x * r0 + wv.y * r1 + wv.z * r2 + wv.w * r3;

        // reduce across the 32-lane group (xor masks < 32 stay in-group)
        #pragma unroll
        for (int m = 1; m < 32; m <<= 1)
            acc += __shfl_xor(acc, m);

        if (lane == 0) {              // acc == Rp[b][l]
            s1 += acc;
            s2 += acc * acc;
        }
    }

    __shared__ float ls1[8], ls2[8];
    if (lane == 0) { ls1[grp] = s1; ls2[grp] = s2; }
    __syncthreads();
    if (tid == 0) {
        float t1 = 0.0f, t2 = 0.0f;
        #pragma unroll
        for (int i = 0; i < 8; ++i) { t1 += ls1[i]; t2 += ls2[i]; }
        ws[b * NCHUNK + chunk]              = t1;
        ws[BS * NCHUNK + b * NCHUNK + chunk] = t2;
    }
}

__global__ __launch_bounds__(256) void final_kernel(
    const float* __restrict__ ws,
    const int*  __restrict__ pred_sz,
    float* __restrict__ out)
{
    const int b = threadIdx.x;   // 256 threads, one per batch
    const int ni = pred_sz[b];
    const int nc = (ni + CHUNK - 1) / CHUNK;   // live chunks for this batch

    float s1 = 0.0f, s2 = 0.0f;
    for (int c = 0; c < nc; ++c) {
        s1 += ws[b * NCHUNK + c];
        s2 += ws[BS * NCHUNK + b * NCHUNK + c];
    }

    const float n  = (float)ni;
    const float E     = s1 / n;
    const float var   = (s2 - n * E * E) / (n - 1.0f);
    const float denom = sqrtf(var + EPS);
    const float sharpe      = E / denom;
    const float sharpe_list = E - LAM / denom;

    __shared__ float red[4][BS];
    red[0][b] = sharpe_list;
    red[1][b] = sharpe;
    red[2][b] = E;
    red[3][b] = var;
    __syncthreads();

    #pragma unroll
    for (int s = BS / 2; s > 0; s >>= 1) {
        if (b < s) {
            red[0][b] += red[0][b + s];
            red[1][b] += red[1][b + s];
            red[2][b] += red[2][b + s];
            red[3][b] += red[3][b + s];
        }
        __syncthreads();
    }

    if (b == 0) {
        out[0] = -red[0][0] / (float)BS;
        out[1] = -red[1][0] / (float)BS;
        out[2] =  red[2][0] / (float)BS;
        out[3] =  red[3][0] / (float)BS;
    }
}

extern "C" void kernel_launch(void* const* d_in, const int* in_sizes, int n_in,
                              void* d_out, int out_size, void* d_ws, size_t ws_size,
                              hipStream_t stream) {
    const float* w     = (const float*)d_in[0];  // pred_weights [256][2048][128]
    const float* price = (const float*)d_in[1];  // price_list   [256][2049][128]
    const int*   psz   = (const int*)d_in[2];    // pred_sz      [256]
    float* out = (float*)d_out;
    float* ws  = (float*)d_ws;

    rp_kernel<<<BS * NCHUNK, 256, 0, stream>>>(w, price, psz, ws);
    final_kernel<<<1, BS, 0, stream>>>(ws, psz, out);
}